// Round 8
// baseline (4737.404 us; speedup 1.0000x reference)
//
#include <hip/hip_runtime.h>

#define T_ 512
#define B_ 64
#define E_ 256
#define H_ 256

typedef __attribute__((ext_vector_type(8))) short short8_t;   // 8 bf16 (4 VGPRs)
typedef __attribute__((ext_vector_type(4))) float floatx4;

__device__ __forceinline__ unsigned short f2bf(float f) {
  unsigned int u = __float_as_uint(f);
  u += 0x7FFFu + ((u >> 16) & 1u);           // RTNE
  return (unsigned short)(u >> 16);
}
__device__ __forceinline__ float bf2f(unsigned short s) {
  return __uint_as_float(((unsigned int)s) << 16);
}
__device__ __forceinline__ float fast_tanh(float x) {
  // tanh(x) = 2/(1+e^{-2x}) - 1 ; exact at saturation, ~1e-7 abs err near 0
  float e = __expf(-2.0f * x);
  return 2.0f / (1.0f + e) - 1.0f;
}

// ---------------------------------------------------------------------------
// Kernel 1: fused q/k projection.  q[t,b,f] = sum_e inp[t,b,e] rot[e,f]
// M = T*B = 32768 flat rows, K=256, N=256.  fp32 (attention needs accuracy).
// ---------------------------------------------------------------------------
__global__ __launch_bounds__(256) void qk_kernel(
    const float* __restrict__ inp, const float* __restrict__ rot,
    const float* __restrict__ ent, float* __restrict__ qo, float* __restrict__ ko)
{
  __shared__ __align__(16) float As[16][136];
  __shared__ __align__(16) float B1[16][68];
  __shared__ __align__(16) float B2[16][68];
  const int tid = threadIdx.x;
  const int m0 = blockIdx.y * 128, n0 = blockIdx.x * 64;
  const int lk = tid & 15, lm = tid >> 4;
  const int ln = tid & 63, lkb = tid >> 6;
  const int tx = tid & 15, ty = tid >> 4;
  float acc1[8][4], acc2[8][4];
#pragma unroll
  for (int i = 0; i < 8; ++i)
#pragma unroll
    for (int j = 0; j < 4; ++j) { acc1[i][j] = 0.f; acc2[i][j] = 0.f; }

  for (int k0 = 0; k0 < 256; k0 += 16) {
    __syncthreads();
#pragma unroll
    for (int p = 0; p < 8; ++p) {
      int m = lm + p * 16;
      As[lk][m] = inp[(size_t)(m0 + m) * 256 + k0 + lk];
    }
#pragma unroll
    for (int p = 0; p < 4; ++p) {
      int kk = lkb + p * 4;
      B1[kk][ln] = rot[(size_t)(k0 + kk) * 256 + n0 + ln];
      B2[kk][ln] = ent[(size_t)(k0 + kk) * 256 + n0 + ln];
    }
    __syncthreads();
#pragma unroll
    for (int kk = 0; kk < 16; ++kk) {
      floatx4 a_lo = *(const floatx4*)&As[kk][ty * 8];
      floatx4 a_hi = *(const floatx4*)&As[kk][ty * 8 + 4];
      floatx4 b1v = *(const floatx4*)&B1[kk][tx * 4];
      floatx4 b2v = *(const floatx4*)&B2[kk][tx * 4];
#pragma unroll
      for (int i = 0; i < 4; ++i) {
        float alo = a_lo[i], ahi = a_hi[i];
#pragma unroll
        for (int j = 0; j < 4; ++j) {
          acc1[i][j]     += alo * b1v[j];
          acc1[i + 4][j] += ahi * b1v[j];
          acc2[i][j]     += alo * b2v[j];
          acc2[i + 4][j] += ahi * b2v[j];
        }
      }
    }
  }
#pragma unroll
  for (int i = 0; i < 8; ++i) {
    size_t row = (size_t)(m0 + ty * 8 + i);
    float4 v1 = make_float4(acc1[i][0], acc1[i][1], acc1[i][2], acc1[i][3]);
    float4 v2 = make_float4(acc2[i][0], acc2[i][1], acc2[i][2], acc2[i][3]);
    *(float4*)&qo[row * 256 + n0 + tx * 4] = v1;
    *(float4*)&ko[row * 256 + n0 + tx * 4] = v2;
  }
}

// ---------------------------------------------------------------------------
// Kernel 2: scores S[b,t,s] = (q[t,b,:] . k[s,b,:]) / 16   (NT, fp32)
// ---------------------------------------------------------------------------
__global__ __launch_bounds__(256) void scores_kernel(
    const float* __restrict__ q, const float* __restrict__ k, float* __restrict__ S)
{
  __shared__ __align__(16) float As[16][136];
  __shared__ __align__(16) float Bs[16][68];
  const int tid = threadIdx.x;
  const int b = blockIdx.z;
  const int m0 = blockIdx.y * 128, n0 = blockIdx.x * 64;
  const int lk = tid & 15, lm = tid >> 4;
  const int tx = tid & 15, ty = tid >> 4;
  float acc[8][4];
#pragma unroll
  for (int i = 0; i < 8; ++i)
#pragma unroll
    for (int j = 0; j < 4; ++j) acc[i][j] = 0.f;

  const float* Ab = q + (size_t)b * 256;
  const float* Bb = k + (size_t)b * 256;
  for (int k0 = 0; k0 < 256; k0 += 16) {
    __syncthreads();
#pragma unroll
    for (int p = 0; p < 8; ++p) {
      int m = lm + p * 16;
      As[lk][m] = Ab[(size_t)(m0 + m) * 16384 + k0 + lk];
    }
#pragma unroll
    for (int p = 0; p < 4; ++p) {
      int n = lm + p * 16;
      Bs[lk][n] = Bb[(size_t)(n0 + n) * 16384 + k0 + lk];
    }
    __syncthreads();
#pragma unroll
    for (int kk = 0; kk < 16; ++kk) {
      floatx4 a_lo = *(const floatx4*)&As[kk][ty * 8];
      floatx4 a_hi = *(const floatx4*)&As[kk][ty * 8 + 4];
      floatx4 bv = *(const floatx4*)&Bs[kk][tx * 4];
#pragma unroll
      for (int i = 0; i < 4; ++i) {
        float alo = a_lo[i], ahi = a_hi[i];
#pragma unroll
        for (int j = 0; j < 4; ++j) {
          acc[i][j]     += alo * bv[j];
          acc[i + 4][j] += ahi * bv[j];
        }
      }
    }
  }
#pragma unroll
  for (int i = 0; i < 8; ++i) {
    size_t off = (size_t)b * 262144 + (size_t)(m0 + ty * 8 + i) * 512 + n0 + tx * 4;
    float4 v = make_float4(acc[i][0] * 0.0625f, acc[i][1] * 0.0625f,
                           acc[i][2] * 0.0625f, acc[i][3] * 0.0625f);
    *(float4*)&S[off] = v;
  }
}

// ---------------------------------------------------------------------------
// Kernel 3: in-place row softmax over 512 elements, 32768 rows.
// ---------------------------------------------------------------------------
__global__ __launch_bounds__(256) void softmax_kernel(float* __restrict__ S)
{
  float* p = S + (size_t)blockIdx.x * 512;
  const int tid = threadIdx.x;
  float x0 = p[tid], x1 = p[tid + 256];
  float m = fmaxf(x0, x1);
#pragma unroll
  for (int off = 32; off > 0; off >>= 1) m = fmaxf(m, __shfl_xor(m, off));
  __shared__ float red[8];
  const int wv = tid >> 6;
  if ((tid & 63) == 0) red[wv] = m;
  __syncthreads();
  m = fmaxf(fmaxf(red[0], red[1]), fmaxf(red[2], red[3]));
  float e0 = __expf(x0 - m);
  float e1 = __expf(x1 - m);
  float s = e0 + e1;
#pragma unroll
  for (int off = 32; off > 0; off >>= 1) s += __shfl_xor(s, off);
  if ((tid & 63) == 0) red[4 + wv] = s;
  __syncthreads();
  s = red[4] + red[5] + red[6] + red[7];
  float r = 1.0f / s;
  p[tid] = e0 * r;
  p[tid + 256] = e1 * r;
}

// ---------------------------------------------------------------------------
// Kernel 4: context[t,b,e] = sum_s P[b,t,s] * inp[s,b,e]   (NN, fp32)
// ---------------------------------------------------------------------------
__global__ __launch_bounds__(256) void context_kernel(
    const float* __restrict__ P, const float* __restrict__ inp, float* __restrict__ ctx)
{
  __shared__ __align__(16) float As[16][136];
  __shared__ __align__(16) float Bs[16][68];
  const int tid = threadIdx.x;
  const int b = blockIdx.z;
  const int m0 = blockIdx.y * 128, e0 = blockIdx.x * 64;
  const int lk = tid & 15, lm = tid >> 4;
  const int ln = tid & 63, lkb = tid >> 6;
  const int tx = tid & 15, ty = tid >> 4;
  float acc[8][4];
#pragma unroll
  for (int i = 0; i < 8; ++i)
#pragma unroll
    for (int j = 0; j < 4; ++j) acc[i][j] = 0.f;

  const float* Ab = P + (size_t)b * 262144;
  for (int k0 = 0; k0 < 512; k0 += 16) {
    __syncthreads();
#pragma unroll
    for (int p = 0; p < 8; ++p) {
      int m = lm + p * 16;
      As[lk][m] = Ab[(size_t)(m0 + m) * 512 + k0 + lk];
    }
#pragma unroll
    for (int p = 0; p < 4; ++p) {
      int kk = lkb + p * 4;
      Bs[kk][ln] = inp[(size_t)(k0 + kk) * 16384 + b * 256 + e0 + ln];
    }
    __syncthreads();
#pragma unroll
    for (int kk = 0; kk < 16; ++kk) {
      floatx4 a_lo = *(const floatx4*)&As[kk][ty * 8];
      floatx4 a_hi = *(const floatx4*)&As[kk][ty * 8 + 4];
      floatx4 bv = *(const floatx4*)&Bs[kk][tx * 4];
#pragma unroll
      for (int i = 0; i < 4; ++i) {
        float alo = a_lo[i], ahi = a_hi[i];
#pragma unroll
        for (int j = 0; j < 4; ++j) {
          acc[i][j]     += alo * bv[j];
          acc[i + 4][j] += ahi * bv[j];
        }
      }
    }
  }
#pragma unroll
  for (int i = 0; i < 8; ++i) {
    size_t off = (size_t)(m0 + ty * 8 + i) * 16384 + (size_t)b * 256 + e0 + tx * 4;
    float4 v = make_float4(acc[i][0], acc[i][1], acc[i][2], acc[i][3]);
    *(float4*)&ctx[off] = v;
  }
}

// ---------------------------------------------------------------------------
// Kernel 5: cp[t,b,h] = bc[h] + sum_e ctx[t,b,e] Wc[e,h]   (fp32)
// ---------------------------------------------------------------------------
__global__ __launch_bounds__(256) void cp_kernel(
    const float* __restrict__ ctx, const float* __restrict__ Wc,
    const float* __restrict__ bc, float* __restrict__ cp)
{
  __shared__ __align__(16) float As[16][136];
  __shared__ __align__(16) float Bs[16][68];
  const int tid = threadIdx.x;
  const int m0 = blockIdx.y * 128, n0 = blockIdx.x * 64;
  const int lk = tid & 15, lm = tid >> 4;
  const int ln = tid & 63, lkb = tid >> 6;
  const int tx = tid & 15, ty = tid >> 4;
  float acc[8][4];
#pragma unroll
  for (int i = 0; i < 8; ++i)
#pragma unroll
    for (int j = 0; j < 4; ++j) acc[i][j] = 0.f;

  for (int k0 = 0; k0 < 256; k0 += 16) {
    __syncthreads();
#pragma unroll
    for (int p = 0; p < 8; ++p) {
      int m = lm + p * 16;
      As[lk][m] = ctx[(size_t)(m0 + m) * 256 + k0 + lk];
    }
#pragma unroll
    for (int p = 0; p < 4; ++p) {
      int kk = lkb + p * 4;
      Bs[kk][ln] = Wc[(size_t)(k0 + kk) * 256 + n0 + ln];
    }
    __syncthreads();
#pragma unroll
    for (int kk = 0; kk < 16; ++kk) {
      floatx4 a_lo = *(const floatx4*)&As[kk][ty * 8];
      floatx4 a_hi = *(const floatx4*)&As[kk][ty * 8 + 4];
      floatx4 bv = *(const floatx4*)&Bs[kk][tx * 4];
#pragma unroll
      for (int i = 0; i < 4; ++i) {
        float alo = a_lo[i], ahi = a_hi[i];
#pragma unroll
        for (int j = 0; j < 4; ++j) {
          acc[i][j]     += alo * bv[j];
          acc[i + 4][j] += ahi * bv[j];
        }
      }
    }
  }
  float b0 = bc[n0 + tx * 4 + 0], b1 = bc[n0 + tx * 4 + 1];
  float b2 = bc[n0 + tx * 4 + 2], b3 = bc[n0 + tx * 4 + 3];
#pragma unroll
  for (int i = 0; i < 8; ++i) {
    size_t row = (size_t)(m0 + ty * 8 + i);
    float4 v = make_float4(acc[i][0] + b0, acc[i][1] + b1, acc[i][2] + b2, acc[i][3] + b3);
    *(float4*)&cp[row * 256 + n0 + tx * 4] = v;
  }
}

// ---------------------------------------------------------------------------
// Kernel 6a: pack gate weights transposed to bf16.  Wt[n][k], n = g*256+h,
// k in [0,512): Wt[n*512+k] = W_g[k][h].  Also bcat[n] = b_g[h].
// ---------------------------------------------------------------------------
__global__ __launch_bounds__(256) void pack_w(
    const float* __restrict__ Wf, const float* __restrict__ Wi,
    const float* __restrict__ Wu, const float* __restrict__ Wo,
    const float* __restrict__ bfv, const float* __restrict__ biv,
    const float* __restrict__ buv, const float* __restrict__ bov,
    unsigned short* __restrict__ Wt, float* __restrict__ bcat)
{
  const int n = blockIdx.x;
  const int g = n >> 8, h = n & 255;
  const float* W = (g == 0) ? Wf : (g == 1) ? Wi : (g == 2) ? Wu : Wo;
  const float* bb = (g == 0) ? bfv : (g == 1) ? biv : (g == 2) ? buv : bov;
  for (int k = threadIdx.x; k < 512; k += 256)
    Wt[(size_t)n * 512 + k] = f2bf(W[(size_t)k * 256 + h]);
  if (threadIdx.x == 0) bcat[n] = bb[h];
}

// ---------------------------------------------------------------------------
// Kernel 6b: pre[m][n'] = bcat[n] + sum_k A[m][k] Wt[n][k]  via bf16 MFMA.
// A = [x | cp] (fp32 sources, converted to bf16 in staging), M=32768, K=512,
// N=1024.  64x64 tile, 4 waves, mfma_f32_16x16x32_bf16.
// OUTPUT LAYOUT: gate-interleaved n' = h*4 + g so the scan reads all 4 gates
// of a cell as one aligned u64.
// ---------------------------------------------------------------------------
__global__ __launch_bounds__(256) void gemm_pre(
    const float* __restrict__ x, const float* __restrict__ cp,
    const unsigned short* __restrict__ Wt, const float* __restrict__ bcat,
    unsigned short* __restrict__ pre)
{
  // row stride 40 shorts (80 B): 16B-aligned b128 reads, 2-way banks (free)
  __shared__ __align__(16) unsigned short As[64 * 40];
  __shared__ __align__(16) unsigned short Bs[64 * 40];
  const int tid = threadIdx.x;
  const int n0 = blockIdx.x * 64, m0 = blockIdx.y * 64;
  const int lane = tid & 63, wv = tid >> 6;
  const int lm = lane & 15, qd = lane >> 4;
  const int sr = tid >> 2, sk = (tid & 3) * 8;   // staging: row 0..63, k-oct 0..3
  floatx4 acc[4] = {{0.f,0.f,0.f,0.f},{0.f,0.f,0.f,0.f},
                    {0.f,0.f,0.f,0.f},{0.f,0.f,0.f,0.f}};
  for (int k0 = 0; k0 < 512; k0 += 32) {
    const float* Asrc = (k0 < 256)
        ? (x  + (size_t)(m0 + sr) * 256 + k0 + sk)
        : (cp + (size_t)(m0 + sr) * 256 + (k0 - 256) + sk);
    float4 a0 = *(const float4*)Asrc;
    float4 a1 = *(const float4*)(Asrc + 4);
    short8_t av;
    av[0] = (short)f2bf(a0.x); av[1] = (short)f2bf(a0.y);
    av[2] = (short)f2bf(a0.z); av[3] = (short)f2bf(a0.w);
    av[4] = (short)f2bf(a1.x); av[5] = (short)f2bf(a1.y);
    av[6] = (short)f2bf(a1.z); av[7] = (short)f2bf(a1.w);
    short8_t bv = *(const short8_t*)&Wt[(size_t)(n0 + sr) * 512 + k0 + sk];
    *(short8_t*)&As[sr * 40 + sk] = av;
    *(short8_t*)&Bs[sr * 40 + sk] = bv;
    __syncthreads();
    short8_t af = *(const short8_t*)&As[(wv * 16 + lm) * 40 + qd * 8];
#pragma unroll
    for (int nt = 0; nt < 4; ++nt) {
      short8_t bf = *(const short8_t*)&Bs[(nt * 16 + lm) * 40 + qd * 8];
      acc[nt] = __builtin_amdgcn_mfma_f32_16x16x32_bf16(af, bf, acc[nt], 0, 0, 0);
    }
    __syncthreads();
  }
#pragma unroll
  for (int nt = 0; nt < 4; ++nt) {
    int col = n0 + nt * 16 + lm;
    float bb = bcat[col];
    int col2 = ((col & 255) << 2) | (col >> 8);   // gate-interleaved
#pragma unroll
    for (int r = 0; r < 4; ++r) {
      int row = m0 + wv * 16 + qd * 4 + r;
      pre[(size_t)row * 1024 + col2] = f2bf(acc[nt][r] + bb);
    }
  }
}

// ---------------------------------------------------------------------------
// Kernel 7: LSTM scan — ALL-LOCAL, Wh STREAMED FROM L2 (register-pipelined).
// 4 WGs x 1024 threads (16 waves, 4/SIMD); WG bg owns batch rows
// [bg*16, bg*16+16).  Wave w computes h-cols [w*16,+16) x ALL 4 gates, so
// each thread owns all 4 gates of its 4 cells -> epilogue fully in-register.
// B-fragments (512 KB/step) stream from L2 (Wcat is 1 MB, L2-resident)
// through a double-buffered register chunk pipeline: load chunk kc+1 while
// MFMA chunk kc; 4 waves/SIMD interleave the residual L2 latency.
// hl double-buffered by t parity; ONE __syncthreads per step.
// No spin loops anywhere -> deadlock impossible by construction.
// ---------------------------------------------------------------------------
__global__ __launch_bounds__(1024, 4) void scan_kernel(
    const unsigned short* __restrict__ pre,   // [32768][1024], col = h*4+g
    const unsigned short* __restrict__ Wt,    // [1024][512],  n = g*256+h
    float* __restrict__ out)
{
  __shared__ __align__(16) unsigned short hl[2][16 * 264];  // h double-buffer
  const int tid = threadIdx.x;
  const int bg = blockIdx.x;           // batch group 0..3 (16 rows)
  const int lane = tid & 63;
  const int w = tid >> 6;              // wave 0..15 -> h-cols [w*16, w*16+16)
  const int qd = lane >> 4;
  const int lm = lane & 15;

  // zero both hl buffers (h(-1) = 0): 2*16*264 shorts = 2112 u64
  {
    unsigned long long* z = (unsigned long long*)hl;
    for (int i = tid; i < 2112; i += 1024) z[i] = 0ull;
  }

  // per-lane B row base pointers for the 4 gates (step-invariant).
  // B-frag for chunk kc lives at wb[g] + kc*32 shorts (imm-offset foldable).
  const unsigned short* wb[4];
#pragma unroll
  for (int g = 0; g < 4; ++g)
    wb[g] = Wt + (size_t)(g * 256 + w * 16 + lm) * 512 + 256 + qd * 8;

  const unsigned long long* pq = (const unsigned long long*)pre;
  const int orow0 = bg * 16 + qd * 4;             // this thread's 4 batch rows
  const int hcol = w * 16 + lm;                   // this thread's h column
  float cst[4] = {0.f, 0.f, 0.f, 0.f};

  short8_t Ba[4], Bb[4];
  // prologue: chunk 0 -> Ba
#pragma unroll
  for (int g = 0; g < 4; ++g) Ba[g] = *(const short8_t*)(wb[g]);

  __syncthreads();   // hl zeros visible

#pragma unroll 1
  for (int t = 0; t < 512; ++t) {
    const unsigned short* hbR = hl[t & 1];
    unsigned short* hbW = hl[(t + 1) & 1];

    // pre loads for this thread's 4 cells (consumed after MFMA phase)
    unsigned long long pcur[4];
    {
      size_t base = (size_t)(t * 64 + orow0) * 256 + hcol;
#pragma unroll
      for (int r = 0; r < 4; ++r)
        pcur[r] = pq[base + (size_t)r * 256];
    }

    // gates(16b x 16col x 4g) = hx(16x256) @ Wh ; B via L2-stream pipeline
    floatx4 acc[4] = {{0.f,0.f,0.f,0.f},{0.f,0.f,0.f,0.f},
                      {0.f,0.f,0.f,0.f},{0.f,0.f,0.f,0.f}};
#pragma unroll
    for (int kc = 0; kc < 8; ++kc) {
      // issue next chunk into the other (named) buffer first
      if (kc < 7) {
        if ((kc & 1) == 0) {
#pragma unroll
          for (int g = 0; g < 4; ++g)
            Bb[g] = *(const short8_t*)(wb[g] + (kc + 1) * 32);
        } else {
#pragma unroll
          for (int g = 0; g < 4; ++g)
            Ba[g] = *(const short8_t*)(wb[g] + (kc + 1) * 32);
        }
      }
      short8_t av = *(const short8_t*)&hbR[lm * 264 + kc * 32 + qd * 8];
      if ((kc & 1) == 0) {
#pragma unroll
        for (int g = 0; g < 4; ++g)
          acc[g] = __builtin_amdgcn_mfma_f32_16x16x32_bf16(av, Ba[g], acc[g], 0, 0, 0);
      } else {
#pragma unroll
        for (int g = 0; g < 4; ++g)
          acc[g] = __builtin_amdgcn_mfma_f32_16x16x32_bf16(av, Bb[g], acc[g], 0, 0, 0);
      }
    }

    // preload chunk 0 for step t+1 (Wt is constant; hides under epilogue VALU)
#pragma unroll
    for (int g = 0; g < 4; ++g) Ba[g] = *(const short8_t*)(wb[g]);

    // activation + cell update (all 4 gates in-thread; no exchange)
#pragma unroll
    for (int r = 0; r < 4; ++r) {
      unsigned long long pv = pcur[r];
      float xf = acc[0][r] + bf2f((unsigned short)pv);
      float xi = acc[1][r] + bf2f((unsigned short)(pv >> 16));
      float xu = acc[2][r] + bf2f((unsigned short)(pv >> 32));
      float xo = acc[3][r] + bf2f((unsigned short)(pv >> 48));
      float fg = 1.0f / (1.0f + __expf(-xf));
      float ig = 1.0f / (1.0f + __expf(-xi));
      float gg = fast_tanh(xu);
      float og = 1.0f / (1.0f + __expf(-xo));
      float cc = fg * cst[r] + ig * gg;
      cst[r] = cc;
      float hh = og * fast_tanh(cc);
      hbW[(qd * 4 + r) * 264 + hcol] = f2bf(hh);          // h(t) for next step
      out[(size_t)t * 16384 + (size_t)(orow0 + r) * 256 + hcol] = hh;
      if (t == 511) {
        const size_t hoff = (size_t)512 * 16384 + (size_t)(orow0 + r) * 256 + hcol;
        out[hoff] = hh;              // hx
        out[hoff + 16384] = cc;      // cx
      }
    }
    __syncthreads();   // hl[(t+1)&1] complete before next step reads it
  }
}

// ---------------------------------------------------------------------------
extern "C" void kernel_launch(void* const* d_in, const int* in_sizes, int n_in,
                              void* d_out, int out_size, void* d_ws, size_t ws_size,
                              hipStream_t stream)
{
  const float* inputs = (const float*)d_in[0];
  const float* rot = (const float*)d_in[1];
  const float* ent = (const float*)d_in[2];
  const float* Wf = (const float*)d_in[3];
  const float* bf_ = (const float*)d_in[4];
  const float* Wi = (const float*)d_in[5];
  const float* bi_ = (const float*)d_in[6];
  const float* Wu = (const float*)d_in[7];
  const float* bu_ = (const float*)d_in[8];
  const float* Wo = (const float*)d_in[9];
  const float* bo_ = (const float*)d_in[10];
  const float* Wc = (const float*)d_in[11];
  const float* bc_ = (const float*)d_in[12];
  float* out = (float*)d_out;

  char* ws = (char*)d_ws;
  float* q  = (float*)(ws);                                   // 32 MiB [T,B,E]
  float* kb = (float*)(ws + (size_t)32 * 1024 * 1024);        // 32 MiB [T,B,E]
  float* S  = (float*)(ws + (size_t)64 * 1024 * 1024);        // 64 MiB [B,T,T]
  unsigned short* pre = (unsigned short*)S;                   // aliases S (dead)
  float* ctx = q;                                             // aliases q (dead)
  float* cp  = kb;                                            // aliases k (dead)
  // q region is dead after cp_kernel -> reuse for packed weights
  unsigned short* Wcat = (unsigned short*)ws;                 // 1 MiB [1024][512]
  float* bcat = (float*)(ws + (size_t)1048576);               // 4 KiB

  qk_kernel<<<dim3(4, 256), 256, 0, stream>>>(inputs, rot, ent, q, kb);
  scores_kernel<<<dim3(8, 4, 64), 256, 0, stream>>>(q, kb, S);
  softmax_kernel<<<dim3(32768), 256, 0, stream>>>(S);
  context_kernel<<<dim3(4, 4, 64), 256, 0, stream>>>(S, inputs, ctx);
  cp_kernel<<<dim3(4, 256), 256, 0, stream>>>(ctx, Wc, bc_, cp);
  pack_w<<<dim3(1024), 256, 0, stream>>>(Wf, Wi, Wu, Wo, bf_, bi_, bu_, bo_,
                                         Wcat, bcat);
  gemm_pre<<<dim3(16, 512), 256, 0, stream>>>(inputs, cp, Wcat, bcat, pre);
  scan_kernel<<<dim3(4), 1024, 0, stream>>>(pre, Wcat, out);
}

// Round 9
// 1800.569 us; speedup vs baseline: 2.6311x; 2.6311x over previous
//
#include <hip/hip_runtime.h>

#define T_ 512
#define B_ 64
#define E_ 256
#define H_ 256

typedef __attribute__((ext_vector_type(8))) short short8_t;   // 8 bf16 (4 VGPRs)
typedef __attribute__((ext_vector_type(4))) float floatx4;

__device__ __forceinline__ unsigned short f2bf(float f) {
  unsigned int u = __float_as_uint(f);
  u += 0x7FFFu + ((u >> 16) & 1u);           // RTNE
  return (unsigned short)(u >> 16);
}
__device__ __forceinline__ float bf2f(unsigned short s) {
  return __uint_as_float(((unsigned int)s) << 16);
}
__device__ __forceinline__ float fast_tanh(float x) {
  // tanh(x) = 2/(1+e^{-2x}) - 1 ; exact at saturation, ~1e-7 abs err near 0
  float e = __expf(-2.0f * x);
  return 2.0f / (1.0f + e) - 1.0f;
}

// ---------------------------------------------------------------------------
// Kernel 1: fused q/k projection.  q[t,b,f] = sum_e inp[t,b,e] rot[e,f]
// M = T*B = 32768 flat rows, K=256, N=256.  fp32 (attention needs accuracy).
// ---------------------------------------------------------------------------
__global__ __launch_bounds__(256) void qk_kernel(
    const float* __restrict__ inp, const float* __restrict__ rot,
    const float* __restrict__ ent, float* __restrict__ qo, float* __restrict__ ko)
{
  __shared__ __align__(16) float As[16][136];
  __shared__ __align__(16) float B1[16][68];
  __shared__ __align__(16) float B2[16][68];
  const int tid = threadIdx.x;
  const int m0 = blockIdx.y * 128, n0 = blockIdx.x * 64;
  const int lk = tid & 15, lm = tid >> 4;
  const int ln = tid & 63, lkb = tid >> 6;
  const int tx = tid & 15, ty = tid >> 4;
  float acc1[8][4], acc2[8][4];
#pragma unroll
  for (int i = 0; i < 8; ++i)
#pragma unroll
    for (int j = 0; j < 4; ++j) { acc1[i][j] = 0.f; acc2[i][j] = 0.f; }

  for (int k0 = 0; k0 < 256; k0 += 16) {
    __syncthreads();
#pragma unroll
    for (int p = 0; p < 8; ++p) {
      int m = lm + p * 16;
      As[lk][m] = inp[(size_t)(m0 + m) * 256 + k0 + lk];
    }
#pragma unroll
    for (int p = 0; p < 4; ++p) {
      int kk = lkb + p * 4;
      B1[kk][ln] = rot[(size_t)(k0 + kk) * 256 + n0 + ln];
      B2[kk][ln] = ent[(size_t)(k0 + kk) * 256 + n0 + ln];
    }
    __syncthreads();
#pragma unroll
    for (int kk = 0; kk < 16; ++kk) {
      floatx4 a_lo = *(const floatx4*)&As[kk][ty * 8];
      floatx4 a_hi = *(const floatx4*)&As[kk][ty * 8 + 4];
      floatx4 b1v = *(const floatx4*)&B1[kk][tx * 4];
      floatx4 b2v = *(const floatx4*)&B2[kk][tx * 4];
#pragma unroll
      for (int i = 0; i < 4; ++i) {
        float alo = a_lo[i], ahi = a_hi[i];
#pragma unroll
        for (int j = 0; j < 4; ++j) {
          acc1[i][j]     += alo * b1v[j];
          acc1[i + 4][j] += ahi * b1v[j];
          acc2[i][j]     += alo * b2v[j];
          acc2[i + 4][j] += ahi * b2v[j];
        }
      }
    }
  }
#pragma unroll
  for (int i = 0; i < 8; ++i) {
    size_t row = (size_t)(m0 + ty * 8 + i);
    float4 v1 = make_float4(acc1[i][0], acc1[i][1], acc1[i][2], acc1[i][3]);
    float4 v2 = make_float4(acc2[i][0], acc2[i][1], acc2[i][2], acc2[i][3]);
    *(float4*)&qo[row * 256 + n0 + tx * 4] = v1;
    *(float4*)&ko[row * 256 + n0 + tx * 4] = v2;
  }
}

// ---------------------------------------------------------------------------
// Kernel 2: scores S[b,t,s] = (q[t,b,:] . k[s,b,:]) / 16   (NT, fp32)
// ---------------------------------------------------------------------------
__global__ __launch_bounds__(256) void scores_kernel(
    const float* __restrict__ q, const float* __restrict__ k, float* __restrict__ S)
{
  __shared__ __align__(16) float As[16][136];
  __shared__ __align__(16) float Bs[16][68];
  const int tid = threadIdx.x;
  const int b = blockIdx.z;
  const int m0 = blockIdx.y * 128, n0 = blockIdx.x * 64;
  const int lk = tid & 15, lm = tid >> 4;
  const int tx = tid & 15, ty = tid >> 4;
  float acc[8][4];
#pragma unroll
  for (int i = 0; i < 8; ++i)
#pragma unroll
    for (int j = 0; j < 4; ++j) acc[i][j] = 0.f;

  const float* Ab = q + (size_t)b * 256;
  const float* Bb = k + (size_t)b * 256;
  for (int k0 = 0; k0 < 256; k0 += 16) {
    __syncthreads();
#pragma unroll
    for (int p = 0; p < 8; ++p) {
      int m = lm + p * 16;
      As[lk][m] = Ab[(size_t)(m0 + m) * 16384 + k0 + lk];
    }
#pragma unroll
    for (int p = 0; p < 4; ++p) {
      int n = lm + p * 16;
      Bs[lk][n] = Bb[(size_t)(n0 + n) * 16384 + k0 + lk];
    }
    __syncthreads();
#pragma unroll
    for (int kk = 0; kk < 16; ++kk) {
      floatx4 a_lo = *(const floatx4*)&As[kk][ty * 8];
      floatx4 a_hi = *(const floatx4*)&As[kk][ty * 8 + 4];
      floatx4 bv = *(const floatx4*)&Bs[kk][tx * 4];
#pragma unroll
      for (int i = 0; i < 4; ++i) {
        float alo = a_lo[i], ahi = a_hi[i];
#pragma unroll
        for (int j = 0; j < 4; ++j) {
          acc[i][j]     += alo * bv[j];
          acc[i + 4][j] += ahi * bv[j];
        }
      }
    }
  }
#pragma unroll
  for (int i = 0; i < 8; ++i) {
    size_t off = (size_t)b * 262144 + (size_t)(m0 + ty * 8 + i) * 512 + n0 + tx * 4;
    float4 v = make_float4(acc[i][0] * 0.0625f, acc[i][1] * 0.0625f,
                           acc[i][2] * 0.0625f, acc[i][3] * 0.0625f);
    *(float4*)&S[off] = v;
  }
}

// ---------------------------------------------------------------------------
// Kernel 3: in-place row softmax over 512 elements, 32768 rows.
// ---------------------------------------------------------------------------
__global__ __launch_bounds__(256) void softmax_kernel(float* __restrict__ S)
{
  float* p = S + (size_t)blockIdx.x * 512;
  const int tid = threadIdx.x;
  float x0 = p[tid], x1 = p[tid + 256];
  float m = fmaxf(x0, x1);
#pragma unroll
  for (int off = 32; off > 0; off >>= 1) m = fmaxf(m, __shfl_xor(m, off));
  __shared__ float red[8];
  const int wv = tid >> 6;
  if ((tid & 63) == 0) red[wv] = m;
  __syncthreads();
  m = fmaxf(fmaxf(red[0], red[1]), fmaxf(red[2], red[3]));
  float e0 = __expf(x0 - m);
  float e1 = __expf(x1 - m);
  float s = e0 + e1;
#pragma unroll
  for (int off = 32; off > 0; off >>= 1) s += __shfl_xor(s, off);
  if ((tid & 63) == 0) red[4 + wv] = s;
  __syncthreads();
  s = red[4] + red[5] + red[6] + red[7];
  float r = 1.0f / s;
  p[tid] = e0 * r;
  p[tid + 256] = e1 * r;
}

// ---------------------------------------------------------------------------
// Kernel 4: context[t,b,e] = sum_s P[b,t,s] * inp[s,b,e]   (NN, fp32)
// ---------------------------------------------------------------------------
__global__ __launch_bounds__(256) void context_kernel(
    const float* __restrict__ P, const float* __restrict__ inp, float* __restrict__ ctx)
{
  __shared__ __align__(16) float As[16][136];
  __shared__ __align__(16) float Bs[16][68];
  const int tid = threadIdx.x;
  const int b = blockIdx.z;
  const int m0 = blockIdx.y * 128, e0 = blockIdx.x * 64;
  const int lk = tid & 15, lm = tid >> 4;
  const int ln = tid & 63, lkb = tid >> 6;
  const int tx = tid & 15, ty = tid >> 4;
  float acc[8][4];
#pragma unroll
  for (int i = 0; i < 8; ++i)
#pragma unroll
    for (int j = 0; j < 4; ++j) acc[i][j] = 0.f;

  const float* Ab = P + (size_t)b * 262144;
  for (int k0 = 0; k0 < 512; k0 += 16) {
    __syncthreads();
#pragma unroll
    for (int p = 0; p < 8; ++p) {
      int m = lm + p * 16;
      As[lk][m] = Ab[(size_t)(m0 + m) * 512 + k0 + lk];
    }
#pragma unroll
    for (int p = 0; p < 4; ++p) {
      int kk = lkb + p * 4;
      Bs[kk][ln] = inp[(size_t)(k0 + kk) * 16384 + b * 256 + e0 + ln];
    }
    __syncthreads();
#pragma unroll
    for (int kk = 0; kk < 16; ++kk) {
      floatx4 a_lo = *(const floatx4*)&As[kk][ty * 8];
      floatx4 a_hi = *(const floatx4*)&As[kk][ty * 8 + 4];
      floatx4 bv = *(const floatx4*)&Bs[kk][tx * 4];
#pragma unroll
      for (int i = 0; i < 4; ++i) {
        float alo = a_lo[i], ahi = a_hi[i];
#pragma unroll
        for (int j = 0; j < 4; ++j) {
          acc[i][j]     += alo * bv[j];
          acc[i + 4][j] += ahi * bv[j];
        }
      }
    }
  }
#pragma unroll
  for (int i = 0; i < 8; ++i) {
    size_t off = (size_t)(m0 + ty * 8 + i) * 16384 + (size_t)b * 256 + e0 + tx * 4;
    float4 v = make_float4(acc[i][0], acc[i][1], acc[i][2], acc[i][3]);
    *(float4*)&ctx[off] = v;
  }
}

// ---------------------------------------------------------------------------
// Kernel 5: cp[t,b,h] = bc[h] + sum_e ctx[t,b,e] Wc[e,h]   (fp32)
// ---------------------------------------------------------------------------
__global__ __launch_bounds__(256) void cp_kernel(
    const float* __restrict__ ctx, const float* __restrict__ Wc,
    const float* __restrict__ bc, float* __restrict__ cp)
{
  __shared__ __align__(16) float As[16][136];
  __shared__ __align__(16) float Bs[16][68];
  const int tid = threadIdx.x;
  const int m0 = blockIdx.y * 128, n0 = blockIdx.x * 64;
  const int lk = tid & 15, lm = tid >> 4;
  const int ln = tid & 63, lkb = tid >> 6;
  const int tx = tid & 15, ty = tid >> 4;
  float acc[8][4];
#pragma unroll
  for (int i = 0; i < 8; ++i)
#pragma unroll
    for (int j = 0; j < 4; ++j) acc[i][j] = 0.f;

  for (int k0 = 0; k0 < 256; k0 += 16) {
    __syncthreads();
#pragma unroll
    for (int p = 0; p < 8; ++p) {
      int m = lm + p * 16;
      As[lk][m] = ctx[(size_t)(m0 + m) * 256 + k0 + lk];
    }
#pragma unroll
    for (int p = 0; p < 4; ++p) {
      int kk = lkb + p * 4;
      Bs[kk][ln] = Wc[(size_t)(k0 + kk) * 256 + n0 + ln];
    }
    __syncthreads();
#pragma unroll
    for (int kk = 0; kk < 16; ++kk) {
      floatx4 a_lo = *(const floatx4*)&As[kk][ty * 8];
      floatx4 a_hi = *(const floatx4*)&As[kk][ty * 8 + 4];
      floatx4 bv = *(const floatx4*)&Bs[kk][tx * 4];
#pragma unroll
      for (int i = 0; i < 4; ++i) {
        float alo = a_lo[i], ahi = a_hi[i];
#pragma unroll
        for (int j = 0; j < 4; ++j) {
          acc[i][j]     += alo * bv[j];
          acc[i + 4][j] += ahi * bv[j];
        }
      }
    }
  }
  float b0 = bc[n0 + tx * 4 + 0], b1 = bc[n0 + tx * 4 + 1];
  float b2 = bc[n0 + tx * 4 + 2], b3 = bc[n0 + tx * 4 + 3];
#pragma unroll
  for (int i = 0; i < 8; ++i) {
    size_t row = (size_t)(m0 + ty * 8 + i);
    float4 v = make_float4(acc[i][0] + b0, acc[i][1] + b1, acc[i][2] + b2, acc[i][3] + b3);
    *(float4*)&cp[row * 256 + n0 + tx * 4] = v;
  }
}

// ---------------------------------------------------------------------------
// Kernel 6a: pack gate weights transposed to bf16.  Wt[n][k], n = g*256+h,
// k in [0,512): Wt[n*512+k] = W_g[k][h].  Also bcat[n] = b_g[h].
// ---------------------------------------------------------------------------
__global__ __launch_bounds__(256) void pack_w(
    const float* __restrict__ Wf, const float* __restrict__ Wi,
    const float* __restrict__ Wu, const float* __restrict__ Wo,
    const float* __restrict__ bfv, const float* __restrict__ biv,
    const float* __restrict__ buv, const float* __restrict__ bov,
    unsigned short* __restrict__ Wt, float* __restrict__ bcat)
{
  const int n = blockIdx.x;
  const int g = n >> 8, h = n & 255;
  const float* W = (g == 0) ? Wf : (g == 1) ? Wi : (g == 2) ? Wu : Wo;
  const float* bb = (g == 0) ? bfv : (g == 1) ? biv : (g == 2) ? buv : bov;
  for (int k = threadIdx.x; k < 512; k += 256)
    Wt[(size_t)n * 512 + k] = f2bf(W[(size_t)k * 256 + h]);
  if (threadIdx.x == 0) bcat[n] = bb[h];
}

// ---------------------------------------------------------------------------
// Kernel 6b: pre[m][n'] = bcat[n] + sum_k A[m][k] Wt[n][k]  via bf16 MFMA.
// A = [x | cp] (fp32 sources, converted to bf16 in staging), M=32768, K=512,
// N=1024.  64x64 tile, 4 waves, mfma_f32_16x16x32_bf16.
// OUTPUT LAYOUT: gate-interleaved n' = h*4 + g so the scan reads all 4 gates
// of a cell as one aligned u64.
// ---------------------------------------------------------------------------
__global__ __launch_bounds__(256) void gemm_pre(
    const float* __restrict__ x, const float* __restrict__ cp,
    const unsigned short* __restrict__ Wt, const float* __restrict__ bcat,
    unsigned short* __restrict__ pre)
{
  // row stride 40 shorts (80 B): 16B-aligned b128 reads, 2-way banks (free)
  __shared__ __align__(16) unsigned short As[64 * 40];
  __shared__ __align__(16) unsigned short Bs[64 * 40];
  const int tid = threadIdx.x;
  const int n0 = blockIdx.x * 64, m0 = blockIdx.y * 64;
  const int lane = tid & 63, wv = tid >> 6;
  const int lm = lane & 15, qd = lane >> 4;
  const int sr = tid >> 2, sk = (tid & 3) * 8;   // staging: row 0..63, k-oct 0..3
  floatx4 acc[4] = {{0.f,0.f,0.f,0.f},{0.f,0.f,0.f,0.f},
                    {0.f,0.f,0.f,0.f},{0.f,0.f,0.f,0.f}};
  for (int k0 = 0; k0 < 512; k0 += 32) {
    const float* Asrc = (k0 < 256)
        ? (x  + (size_t)(m0 + sr) * 256 + k0 + sk)
        : (cp + (size_t)(m0 + sr) * 256 + (k0 - 256) + sk);
    float4 a0 = *(const float4*)Asrc;
    float4 a1 = *(const float4*)(Asrc + 4);
    short8_t av;
    av[0] = (short)f2bf(a0.x); av[1] = (short)f2bf(a0.y);
    av[2] = (short)f2bf(a0.z); av[3] = (short)f2bf(a0.w);
    av[4] = (short)f2bf(a1.x); av[5] = (short)f2bf(a1.y);
    av[6] = (short)f2bf(a1.z); av[7] = (short)f2bf(a1.w);
    short8_t bv = *(const short8_t*)&Wt[(size_t)(n0 + sr) * 512 + k0 + sk];
    *(short8_t*)&As[sr * 40 + sk] = av;
    *(short8_t*)&Bs[sr * 40 + sk] = bv;
    __syncthreads();
    short8_t af = *(const short8_t*)&As[(wv * 16 + lm) * 40 + qd * 8];
#pragma unroll
    for (int nt = 0; nt < 4; ++nt) {
      short8_t bf = *(const short8_t*)&Bs[(nt * 16 + lm) * 40 + qd * 8];
      acc[nt] = __builtin_amdgcn_mfma_f32_16x16x32_bf16(af, bf, acc[nt], 0, 0, 0);
    }
    __syncthreads();
  }
#pragma unroll
  for (int nt = 0; nt < 4; ++nt) {
    int col = n0 + nt * 16 + lm;
    float bb = bcat[col];
    int col2 = ((col & 255) << 2) | (col >> 8);   // gate-interleaved
#pragma unroll
    for (int r = 0; r < 4; ++r) {
      int row = m0 + wv * 16 + qd * 4 + r;
      pre[(size_t)row * 1024 + col2] = f2bf(acc[nt][r] + bb);
    }
  }
}

// ---------------------------------------------------------------------------
// Kernel 7: persistent LSTM scan — round-4 structure + XCD CO-LOCATION.
// Logical topology unchanged: 16 working WGs = 4 batch-groups x 4 h-blocks,
// write-once NaN-sentinel data-polled exchange, Wh in regs, 1 barrier/step.
// NEW: grid = 32 and bg = blockIdx&7 (exit if >=4), cg = blockIdx>>3 — under
// the round-robin blockIdx->XCD mapping (T1/m157), all 4 members of group bg
// land on XCD bg, so the hxT publish/poll stays inside ONE XCD's L2
// (agent-scope coherence point) instead of crossing the die fabric.
// If the mapping assumption is false this is merely a random placement —
// identical semantics, round-4 performance.
// ---------------------------------------------------------------------------
__global__ __launch_bounds__(256, 1) void scan_kernel(
    const unsigned short* __restrict__ pre,   // [32768][1024], col = h*4+g
    const unsigned short* __restrict__ Wt,    // [1024][512],  n = g*256+h
    float* __restrict__ out, unsigned long long* __restrict__ hxT)
{
  const int xcd = blockIdx.x & 7;
  if (xcd >= 4) return;                // 16 idle WGs exit immediately
  const int bg = xcd;                  // batch group 0..3 == target XCD
  const int cg = blockIdx.x >> 3;      // h-block 0..3 (64 cols)

  __shared__ __align__(16) unsigned short hl[2][16 * 264];  // h double-buffer
  const int tid = threadIdx.x;
  const int lane = tid & 63;
  const int w = tid >> 6;              // wave 0..3 -> cols [w*16, w*16+16)
  const int qd = lane >> 4;
  const int lh = lane & 15;

  // zero both hl buffers (h(-1) = 0): 2*16*264 shorts = 2112 u64
  {
    unsigned long long* z = (unsigned long long*)hl;
    for (int i = tid; i < 2112; i += 256) z[i] = 0ull;
  }

  // Wh B-fragments -> VGPRs (once).  wreg[g][kc]: 16col x 32k tile fragment.
  short8_t wreg[4][8];
#pragma unroll
  for (int g = 0; g < 4; ++g)
#pragma unroll
    for (int kc = 0; kc < 8; ++kc)
      wreg[g][kc] = *(const short8_t*)&Wt[(size_t)(g * 256 + cg * 64 + w * 16 + lh) * 512
                                          + 256 + kc * 32 + qd * 8];

  const unsigned long long* pq = (const unsigned long long*)pre;
  const int orow0 = bg * 16 + qd * 4;             // this thread's 4 batch rows
  const int hcol = cg * 64 + w * 16 + lh;         // this thread's h column
  unsigned long long pcur[4], pnext[4];
#pragma unroll
  for (int r = 0; r < 4; ++r)
    pcur[r] = pq[(size_t)(orow0 + r) * 256 + hcol];

  float cst[4] = {0.f, 0.f, 0.f, 0.f};
  const int cg1 = (cg + 1) & 3, cg2 = (cg + 2) & 3, cg3 = (cg + 3) & 3;
  const int prow = tid >> 4, pcolq = tid & 15;    // poll/assemble coords

  __syncthreads();   // zeros visible

#pragma unroll 1
  for (int t = 0; t < 512; ++t) {
    unsigned long long* hlqR = (unsigned long long*)hl[t & 1];        // read buf
    unsigned long long* hlqW = (unsigned long long*)hl[(t + 1) & 1];  // write buf

    if (t > 0) {
      // poll peers' h(t-1) slices (write-once, NaN-sentinel); assemble to hlR
      const unsigned long long* sbase = hxT + (size_t)((t - 1) * 4 + bg) * 1024;
      const unsigned long long* s0 = sbase + (size_t)cg1 * 256;
      const unsigned long long* s1 = sbase + (size_t)cg2 * 256;
      const unsigned long long* s2 = sbase + (size_t)cg3 * 256;
      unsigned long long d0, d1, d2;
      bool ok;
      do {
        d0 = __hip_atomic_load(&s0[tid], __ATOMIC_RELAXED, __HIP_MEMORY_SCOPE_AGENT);
        d1 = __hip_atomic_load(&s1[tid], __ATOMIC_RELAXED, __HIP_MEMORY_SCOPE_AGENT);
        d2 = __hip_atomic_load(&s2[tid], __ATOMIC_RELAXED, __HIP_MEMORY_SCOPE_AGENT);
        ok = ((unsigned int)d0 != 0xFFFFFFFFu) && ((unsigned int)(d0 >> 32) != 0xFFFFFFFFu)
          && ((unsigned int)d1 != 0xFFFFFFFFu) && ((unsigned int)(d1 >> 32) != 0xFFFFFFFFu)
          && ((unsigned int)d2 != 0xFFFFFFFFu) && ((unsigned int)(d2 >> 32) != 0xFFFFFFFFu);
      } while (!__all((int)ok));
      hlqR[prow * 66 + cg1 * 16 + pcolq] = d0;
      hlqR[prow * 66 + cg2 * 16 + pcolq] = d1;
      hlqR[prow * 66 + cg3 * 16 + pcolq] = d2;
    }

    // prefetch pre(t+1): consumed after MFMA, one full phase of slack
    if (t < 511) {
      size_t base = (size_t)((t + 1) * 64 + orow0) * 256 + hcol;
#pragma unroll
      for (int r = 0; r < 4; ++r)
        pnext[r] = pq[base + (size_t)r * 256];
    }

    __syncthreads();   // hlR fully assembled; hlW free (all prior reads done)

    // gates(16b x 16col x 4g) = hx(16x256) @ Wh ; B from VGPRs
    const unsigned short* hb = hl[t & 1];
    floatx4 acc[4] = {{0.f,0.f,0.f,0.f},{0.f,0.f,0.f,0.f},
                      {0.f,0.f,0.f,0.f},{0.f,0.f,0.f,0.f}};
#pragma unroll
    for (int kc = 0; kc < 8; ++kc) {
      short8_t av = *(const short8_t*)&hb[lh * 264 + kc * 32 + qd * 8];
#pragma unroll
      for (int g = 0; g < 4; ++g)
        acc[g] = __builtin_amdgcn_mfma_f32_16x16x32_bf16(av, wreg[g][kc], acc[g], 0, 0, 0);
    }

    // activation + cell update (fully in-register; col = hcol, rows orow0+r)
    float h[4];
#pragma unroll
    for (int r = 0; r < 4; ++r) {
      unsigned long long pv = pcur[r];
      float xf = acc[0][r] + bf2f((unsigned short)pv);
      float xi = acc[1][r] + bf2f((unsigned short)(pv >> 16));
      float xu = acc[2][r] + bf2f((unsigned short)(pv >> 32));
      float xo = acc[3][r] + bf2f((unsigned short)(pv >> 48));
      float fg = 1.0f / (1.0f + __expf(-xf));
      float ig = 1.0f / (1.0f + __expf(-xi));
      float gg = fast_tanh(xu);
      float og = 1.0f / (1.0f + __expf(-xo));
      float cc = fg * cst[r] + ig * gg;
      cst[r] = cc;
      h[r] = og * fast_tanh(cc);
    }

    // 4x4 in-quad transpose: lane ends with row qd*4+(lane&3), 4 cols
    float t0c, t1c, t2c, t3c;
    {
      float e0 = __shfl_xor(h[0], 1);
      float e1 = __shfl_xor(h[1], 1);
      float e2 = __shfl_xor(h[2], 1);
      float e3 = __shfl_xor(h[3], 1);
      bool odd = (lane & 1);
      float b0 = odd ? e1 : h[0];
      float b1 = odd ? h[1] : e0;
      float b2 = odd ? e3 : h[2];
      float b3 = odd ? h[3] : e2;
      float f0 = __shfl_xor(b0, 2);
      float f1 = __shfl_xor(b1, 2);
      float f2 = __shfl_xor(b2, 2);
      float f3 = __shfl_xor(b3, 2);
      bool hi = (lane & 2);
      t0c = hi ? f2 : b0;
      t1c = hi ? f3 : b1;
      t2c = hi ? b2 : f0;
      t3c = hi ? b3 : f1;
    }
    unsigned long long hp = (unsigned long long)f2bf(t0c)
        | ((unsigned long long)f2bf(t1c) << 16)
        | ((unsigned long long)f2bf(t2c) << 32)
        | ((unsigned long long)f2bf(t3c) << 48);
    const int orow = qd * 4 + (lane & 3);          // transposed row 0..15
    const int ocolq = w * 4 + (lh >> 2);           // col-quad within 64-stripe

    // publish FIRST (critical path for peers), then local hlW + out
    __hip_atomic_store(&hxT[(size_t)((t * 4 + bg) * 4 + cg) * 256 + orow * 16 + ocolq],
                       hp, __ATOMIC_RELAXED, __HIP_MEMORY_SCOPE_AGENT);
    hlqW[orow * 66 + cg * 16 + ocolq] = hp;
    *(float4*)&out[(size_t)t * 16384 + (size_t)(bg * 16 + orow) * 256 + cg * 64 + ocolq * 4]
        = make_float4(t0c, t1c, t2c, t3c);

    if (t == 511) {
      const size_t hoff = (size_t)512 * 16384;
#pragma unroll
      for (int r = 0; r < 4; ++r) {
        out[hoff + (size_t)(orow0 + r) * 256 + hcol] = h[r];            // hx
        out[hoff + 16384 + (size_t)(orow0 + r) * 256 + hcol] = cst[r];  // cx
      }
    }
#pragma unroll
    for (int r = 0; r < 4; ++r) pcur[r] = pnext[r];
  }
}

// ---------------------------------------------------------------------------
extern "C" void kernel_launch(void* const* d_in, const int* in_sizes, int n_in,
                              void* d_out, int out_size, void* d_ws, size_t ws_size,
                              hipStream_t stream)
{
  const float* inputs = (const float*)d_in[0];
  const float* rot = (const float*)d_in[1];
  const float* ent = (const float*)d_in[2];
  const float* Wf = (const float*)d_in[3];
  const float* bf_ = (const float*)d_in[4];
  const float* Wi = (const float*)d_in[5];
  const float* bi_ = (const float*)d_in[6];
  const float* Wu = (const float*)d_in[7];
  const float* bu_ = (const float*)d_in[8];
  const float* Wo = (const float*)d_in[9];
  const float* bo_ = (const float*)d_in[10];
  const float* Wc = (const float*)d_in[11];
  const float* bc_ = (const float*)d_in[12];
  float* out = (float*)d_out;

  char* ws = (char*)d_ws;
  float* q  = (float*)(ws);                                   // 32 MiB [T,B,E]
  float* kb = (float*)(ws + (size_t)32 * 1024 * 1024);        // 32 MiB [T,B,E]
  float* S  = (float*)(ws + (size_t)64 * 1024 * 1024);        // 64 MiB [B,T,T]
  unsigned short* pre = (unsigned short*)S;                   // aliases S (dead)
  float* ctx = q;                                             // aliases q (dead)
  float* cp  = kb;                                            // aliases k (dead)
  // q region is dead after cp_kernel -> reuse for packed weights + hx timeline
  unsigned short* Wcat = (unsigned short*)ws;                 // 1 MiB [1024][512]
  float* bcat = (float*)(ws + (size_t)1048576);               // 4 KiB
  unsigned long long* hxT =
      (unsigned long long*)(ws + (size_t)2 * 1024 * 1024);    // 16 MiB [512][4][4][256]

  qk_kernel<<<dim3(4, 256), 256, 0, stream>>>(inputs, rot, ent, q, kb);
  scores_kernel<<<dim3(8, 4, 64), 256, 0, stream>>>(q, kb, S);
  softmax_kernel<<<dim3(32768), 256, 0, stream>>>(S);
  context_kernel<<<dim3(4, 4, 64), 256, 0, stream>>>(S, inputs, ctx);
  cp_kernel<<<dim3(4, 256), 256, 0, stream>>>(ctx, Wc, bc_, cp);
  // q region dead now: prefill hx timeline with 0xFF (bf16 NaN sentinel)
  hipMemsetAsync(hxT, 0xFF, (size_t)16 * 1024 * 1024, stream);
  pack_w<<<dim3(1024), 256, 0, stream>>>(Wf, Wi, Wu, Wo, bf_, bi_, bu_, bo_,
                                         Wcat, bcat);
  gemm_pre<<<dim3(16, 512), 256, 0, stream>>>(inputs, cp, Wcat, bcat, pre);
  scan_kernel<<<dim3(32), 256, 0, stream>>>(pre, Wcat, out, hxT);
}

// Round 10
// 1720.083 us; speedup vs baseline: 2.7542x; 1.0468x over previous
//
#include <hip/hip_runtime.h>

#define T_ 512
#define B_ 64
#define E_ 256
#define H_ 256

typedef __attribute__((ext_vector_type(8))) short short8_t;   // 8 bf16 (4 VGPRs)
typedef __attribute__((ext_vector_type(4))) float floatx4;

__device__ __forceinline__ unsigned short f2bf(float f) {
  unsigned int u = __float_as_uint(f);
  u += 0x7FFFu + ((u >> 16) & 1u);           // RTNE
  return (unsigned short)(u >> 16);
}
__device__ __forceinline__ float bf2f(unsigned short s) {
  return __uint_as_float(((unsigned int)s) << 16);
}
__device__ __forceinline__ float fast_tanh(float x) {
  // tanh(x) = 2/(1+e^{-2x}) - 1 ; exact at saturation, ~1e-7 abs err near 0
  float e = __expf(-2.0f * x);
  return 2.0f / (1.0f + e) - 1.0f;
}

// ---------------------------------------------------------------------------
// Kernel 1: fused q/k projection.  q[t,b,f] = sum_e inp[t,b,e] rot[e,f]
// M = T*B = 32768 flat rows, K=256, N=256.  fp32 (attention needs accuracy).
// ---------------------------------------------------------------------------
__global__ __launch_bounds__(256) void qk_kernel(
    const float* __restrict__ inp, const float* __restrict__ rot,
    const float* __restrict__ ent, float* __restrict__ qo, float* __restrict__ ko)
{
  __shared__ __align__(16) float As[16][136];
  __shared__ __align__(16) float B1[16][68];
  __shared__ __align__(16) float B2[16][68];
  const int tid = threadIdx.x;
  const int m0 = blockIdx.y * 128, n0 = blockIdx.x * 64;
  const int lk = tid & 15, lm = tid >> 4;
  const int ln = tid & 63, lkb = tid >> 6;
  const int tx = tid & 15, ty = tid >> 4;
  float acc1[8][4], acc2[8][4];
#pragma unroll
  for (int i = 0; i < 8; ++i)
#pragma unroll
    for (int j = 0; j < 4; ++j) { acc1[i][j] = 0.f; acc2[i][j] = 0.f; }

  for (int k0 = 0; k0 < 256; k0 += 16) {
    __syncthreads();
#pragma unroll
    for (int p = 0; p < 8; ++p) {
      int m = lm + p * 16;
      As[lk][m] = inp[(size_t)(m0 + m) * 256 + k0 + lk];
    }
#pragma unroll
    for (int p = 0; p < 4; ++p) {
      int kk = lkb + p * 4;
      B1[kk][ln] = rot[(size_t)(k0 + kk) * 256 + n0 + ln];
      B2[kk][ln] = ent[(size_t)(k0 + kk) * 256 + n0 + ln];
    }
    __syncthreads();
#pragma unroll
    for (int kk = 0; kk < 16; ++kk) {
      floatx4 a_lo = *(const floatx4*)&As[kk][ty * 8];
      floatx4 a_hi = *(const floatx4*)&As[kk][ty * 8 + 4];
      floatx4 b1v = *(const floatx4*)&B1[kk][tx * 4];
      floatx4 b2v = *(const floatx4*)&B2[kk][tx * 4];
#pragma unroll
      for (int i = 0; i < 4; ++i) {
        float alo = a_lo[i], ahi = a_hi[i];
#pragma unroll
        for (int j = 0; j < 4; ++j) {
          acc1[i][j]     += alo * b1v[j];
          acc1[i + 4][j] += ahi * b1v[j];
          acc2[i][j]     += alo * b2v[j];
          acc2[i + 4][j] += ahi * b2v[j];
        }
      }
    }
  }
#pragma unroll
  for (int i = 0; i < 8; ++i) {
    size_t row = (size_t)(m0 + ty * 8 + i);
    float4 v1 = make_float4(acc1[i][0], acc1[i][1], acc1[i][2], acc1[i][3]);
    float4 v2 = make_float4(acc2[i][0], acc2[i][1], acc2[i][2], acc2[i][3]);
    *(float4*)&qo[row * 256 + n0 + tx * 4] = v1;
    *(float4*)&ko[row * 256 + n0 + tx * 4] = v2;
  }
}

// ---------------------------------------------------------------------------
// Kernel 2: scores S[b,t,s] = (q[t,b,:] . k[s,b,:]) / 16   (NT, fp32)
// 128x128 tile, 8x8 acc/thread: 64 FMA per kk vs 4 b128 LDS reads
// -> VALU-bound (was 128x64 / 8x4: 32 FMA vs 3 reads, LDS-issue-bound).
// ---------------------------------------------------------------------------
__global__ __launch_bounds__(256) void scores_kernel(
    const float* __restrict__ q, const float* __restrict__ k, float* __restrict__ S)
{
  __shared__ __align__(16) float As[16][136];
  __shared__ __align__(16) float Bs[16][136];
  const int tid = threadIdx.x;
  const int b = blockIdx.z;
  const int m0 = blockIdx.y * 128, n0 = blockIdx.x * 128;
  const int lk = tid & 15, lm = tid >> 4;
  const int tx = tid & 15, ty = tid >> 4;
  float acc[8][8];
#pragma unroll
  for (int i = 0; i < 8; ++i)
#pragma unroll
    for (int j = 0; j < 8; ++j) acc[i][j] = 0.f;

  const float* Ab = q + (size_t)b * 256;
  const float* Bb = k + (size_t)b * 256;
  for (int k0 = 0; k0 < 256; k0 += 16) {
    __syncthreads();
#pragma unroll
    for (int p = 0; p < 8; ++p) {
      int m = lm + p * 16;
      As[lk][m] = Ab[(size_t)(m0 + m) * 16384 + k0 + lk];
      Bs[lk][m] = Bb[(size_t)(n0 + m) * 16384 + k0 + lk];
    }
    __syncthreads();
#pragma unroll
    for (int kk = 0; kk < 16; ++kk) {
      floatx4 a_lo = *(const floatx4*)&As[kk][ty * 8];
      floatx4 a_hi = *(const floatx4*)&As[kk][ty * 8 + 4];
      floatx4 b_lo = *(const floatx4*)&Bs[kk][tx * 8];
      floatx4 b_hi = *(const floatx4*)&Bs[kk][tx * 8 + 4];
      float av[8], bv[8];
#pragma unroll
      for (int i = 0; i < 4; ++i) { av[i] = a_lo[i]; av[i + 4] = a_hi[i];
                                    bv[i] = b_lo[i]; bv[i + 4] = b_hi[i]; }
#pragma unroll
      for (int i = 0; i < 8; ++i)
#pragma unroll
        for (int j = 0; j < 8; ++j)
          acc[i][j] += av[i] * bv[j];
    }
  }
#pragma unroll
  for (int i = 0; i < 8; ++i) {
    size_t off = (size_t)b * 262144 + (size_t)(m0 + ty * 8 + i) * 512 + n0 + tx * 8;
    float4 v0 = make_float4(acc[i][0] * 0.0625f, acc[i][1] * 0.0625f,
                            acc[i][2] * 0.0625f, acc[i][3] * 0.0625f);
    float4 v1 = make_float4(acc[i][4] * 0.0625f, acc[i][5] * 0.0625f,
                            acc[i][6] * 0.0625f, acc[i][7] * 0.0625f);
    *(float4*)&S[off] = v0;
    *(float4*)&S[off + 4] = v1;
  }
}

// ---------------------------------------------------------------------------
// Kernel 3: in-place row softmax over 512 elements, 32768 rows.
// ---------------------------------------------------------------------------
__global__ __launch_bounds__(256) void softmax_kernel(float* __restrict__ S)
{
  float* p = S + (size_t)blockIdx.x * 512;
  const int tid = threadIdx.x;
  float x0 = p[tid], x1 = p[tid + 256];
  float m = fmaxf(x0, x1);
#pragma unroll
  for (int off = 32; off > 0; off >>= 1) m = fmaxf(m, __shfl_xor(m, off));
  __shared__ float red[8];
  const int wv = tid >> 6;
  if ((tid & 63) == 0) red[wv] = m;
  __syncthreads();
  m = fmaxf(fmaxf(red[0], red[1]), fmaxf(red[2], red[3]));
  float e0 = __expf(x0 - m);
  float e1 = __expf(x1 - m);
  float s = e0 + e1;
#pragma unroll
  for (int off = 32; off > 0; off >>= 1) s += __shfl_xor(s, off);
  if ((tid & 63) == 0) red[4 + wv] = s;
  __syncthreads();
  s = red[4] + red[5] + red[6] + red[7];
  float r = 1.0f / s;
  p[tid] = e0 * r;
  p[tid + 256] = e1 * r;
}

// ---------------------------------------------------------------------------
// Kernel 4: context[t,b,e] = sum_s P[b,t,s] * inp[s,b,e]   (NN, fp32)
// 128x128 tile, 8x8 acc/thread (VALU-bound; was 128x64 / 8x4).
// ---------------------------------------------------------------------------
__global__ __launch_bounds__(256) void context_kernel(
    const float* __restrict__ P, const float* __restrict__ inp, float* __restrict__ ctx)
{
  __shared__ __align__(16) float As[16][136];
  __shared__ __align__(16) float Bs[16][136];
  const int tid = threadIdx.x;
  const int b = blockIdx.z;
  const int m0 = blockIdx.y * 128, e0 = blockIdx.x * 128;
  const int lk = tid & 15, lm = tid >> 4;
  const int tx = tid & 15, ty = tid >> 4;
  const int bk = tid >> 7, be = tid & 127;   // B staging: 2 kk x 128 e per pass
  float acc[8][8];
#pragma unroll
  for (int i = 0; i < 8; ++i)
#pragma unroll
    for (int j = 0; j < 8; ++j) acc[i][j] = 0.f;

  const float* Ab = P + (size_t)b * 262144;
  for (int k0 = 0; k0 < 512; k0 += 16) {
    __syncthreads();
#pragma unroll
    for (int p = 0; p < 8; ++p) {
      int m = lm + p * 16;
      As[lk][m] = Ab[(size_t)(m0 + m) * 512 + k0 + lk];
    }
#pragma unroll
    for (int p = 0; p < 8; ++p) {
      int kk = bk + p * 2;
      Bs[kk][be] = inp[(size_t)(k0 + kk) * 16384 + b * 256 + e0 + be];
    }
    __syncthreads();
#pragma unroll
    for (int kk = 0; kk < 16; ++kk) {
      floatx4 a_lo = *(const floatx4*)&As[kk][ty * 8];
      floatx4 a_hi = *(const floatx4*)&As[kk][ty * 8 + 4];
      floatx4 b_lo = *(const floatx4*)&Bs[kk][tx * 8];
      floatx4 b_hi = *(const floatx4*)&Bs[kk][tx * 8 + 4];
      float av[8], bv[8];
#pragma unroll
      for (int i = 0; i < 4; ++i) { av[i] = a_lo[i]; av[i + 4] = a_hi[i];
                                    bv[i] = b_lo[i]; bv[i + 4] = b_hi[i]; }
#pragma unroll
      for (int i = 0; i < 8; ++i)
#pragma unroll
        for (int j = 0; j < 8; ++j)
          acc[i][j] += av[i] * bv[j];
    }
  }
#pragma unroll
  for (int i = 0; i < 8; ++i) {
    size_t off = (size_t)(m0 + ty * 8 + i) * 16384 + (size_t)b * 256 + e0 + tx * 8;
    float4 v0 = make_float4(acc[i][0], acc[i][1], acc[i][2], acc[i][3]);
    float4 v1 = make_float4(acc[i][4], acc[i][5], acc[i][6], acc[i][7]);
    *(float4*)&ctx[off] = v0;
    *(float4*)&ctx[off + 4] = v1;
  }
}

// ---------------------------------------------------------------------------
// Kernel 5: cp[t,b,h] = bc[h] + sum_e ctx[t,b,e] Wc[e,h]   (fp32)
// ---------------------------------------------------------------------------
__global__ __launch_bounds__(256) void cp_kernel(
    const float* __restrict__ ctx, const float* __restrict__ Wc,
    const float* __restrict__ bc, float* __restrict__ cp)
{
  __shared__ __align__(16) float As[16][136];
  __shared__ __align__(16) float Bs[16][68];
  const int tid = threadIdx.x;
  const int m0 = blockIdx.y * 128, n0 = blockIdx.x * 64;
  const int lk = tid & 15, lm = tid >> 4;
  const int ln = tid & 63, lkb = tid >> 6;
  const int tx = tid & 15, ty = tid >> 4;
  float acc[8][4];
#pragma unroll
  for (int i = 0; i < 8; ++i)
#pragma unroll
    for (int j = 0; j < 4; ++j) acc[i][j] = 0.f;

  for (int k0 = 0; k0 < 256; k0 += 16) {
    __syncthreads();
#pragma unroll
    for (int p = 0; p < 8; ++p) {
      int m = lm + p * 16;
      As[lk][m] = ctx[(size_t)(m0 + m) * 256 + k0 + lk];
    }
#pragma unroll
    for (int p = 0; p < 4; ++p) {
      int kk = lkb + p * 4;
      Bs[kk][ln] = Wc[(size_t)(k0 + kk) * 256 + n0 + ln];
    }
    __syncthreads();
#pragma unroll
    for (int kk = 0; kk < 16; ++kk) {
      floatx4 a_lo = *(const floatx4*)&As[kk][ty * 8];
      floatx4 a_hi = *(const floatx4*)&As[kk][ty * 8 + 4];
      floatx4 bv = *(const floatx4*)&Bs[kk][tx * 4];
#pragma unroll
      for (int i = 0; i < 4; ++i) {
        float alo = a_lo[i], ahi = a_hi[i];
#pragma unroll
        for (int j = 0; j < 4; ++j) {
          acc[i][j]     += alo * bv[j];
          acc[i + 4][j] += ahi * bv[j];
        }
      }
    }
  }
  float b0 = bc[n0 + tx * 4 + 0], b1 = bc[n0 + tx * 4 + 1];
  float b2 = bc[n0 + tx * 4 + 2], b3 = bc[n0 + tx * 4 + 3];
#pragma unroll
  for (int i = 0; i < 8; ++i) {
    size_t row = (size_t)(m0 + ty * 8 + i);
    float4 v = make_float4(acc[i][0] + b0, acc[i][1] + b1, acc[i][2] + b2, acc[i][3] + b3);
    *(float4*)&cp[row * 256 + n0 + tx * 4] = v;
  }
}

// ---------------------------------------------------------------------------
// Kernel 6a: pack gate weights transposed to bf16.  Wt[n][k], n = g*256+h,
// k in [0,512): Wt[n*512+k] = W_g[k][h].  Also bcat[n] = b_g[h].
// ---------------------------------------------------------------------------
__global__ __launch_bounds__(256) void pack_w(
    const float* __restrict__ Wf, const float* __restrict__ Wi,
    const float* __restrict__ Wu, const float* __restrict__ Wo,
    const float* __restrict__ bfv, const float* __restrict__ biv,
    const float* __restrict__ buv, const float* __restrict__ bov,
    unsigned short* __restrict__ Wt, float* __restrict__ bcat)
{
  const int n = blockIdx.x;
  const int g = n >> 8, h = n & 255;
  const float* W = (g == 0) ? Wf : (g == 1) ? Wi : (g == 2) ? Wu : Wo;
  const float* bb = (g == 0) ? bfv : (g == 1) ? biv : (g == 2) ? buv : bov;
  for (int k = threadIdx.x; k < 512; k += 256)
    Wt[(size_t)n * 512 + k] = f2bf(W[(size_t)k * 256 + h]);
  if (threadIdx.x == 0) bcat[n] = bb[h];
}

// ---------------------------------------------------------------------------
// Kernel 6b: pre[m][n'] = bcat[n] + sum_k A[m][k] Wt[n][k]  via bf16 MFMA.
// A = [x | cp] (fp32 sources, converted to bf16 in staging), M=32768, K=512,
// N=1024.  64x64 tile, 4 waves, mfma_f32_16x16x32_bf16.
// OUTPUT LAYOUT: gate-interleaved n' = h*4 + g so the scan reads all 4 gates
// of a cell as one aligned u64.
// ---------------------------------------------------------------------------
__global__ __launch_bounds__(256) void gemm_pre(
    const float* __restrict__ x, const float* __restrict__ cp,
    const unsigned short* __restrict__ Wt, const float* __restrict__ bcat,
    unsigned short* __restrict__ pre)
{
  // row stride 40 shorts (80 B): 16B-aligned b128 reads, 2-way banks (free)
  __shared__ __align__(16) unsigned short As[64 * 40];
  __shared__ __align__(16) unsigned short Bs[64 * 40];
  const int tid = threadIdx.x;
  const int n0 = blockIdx.x * 64, m0 = blockIdx.y * 64;
  const int lane = tid & 63, wv = tid >> 6;
  const int lm = lane & 15, qd = lane >> 4;
  const int sr = tid >> 2, sk = (tid & 3) * 8;   // staging: row 0..63, k-oct 0..3
  floatx4 acc[4] = {{0.f,0.f,0.f,0.f},{0.f,0.f,0.f,0.f},
                    {0.f,0.f,0.f,0.f},{0.f,0.f,0.f,0.f}};
  for (int k0 = 0; k0 < 512; k0 += 32) {
    const float* Asrc = (k0 < 256)
        ? (x  + (size_t)(m0 + sr) * 256 + k0 + sk)
        : (cp + (size_t)(m0 + sr) * 256 + (k0 - 256) + sk);
    float4 a0 = *(const float4*)Asrc;
    float4 a1 = *(const float4*)(Asrc + 4);
    short8_t av;
    av[0] = (short)f2bf(a0.x); av[1] = (short)f2bf(a0.y);
    av[2] = (short)f2bf(a0.z); av[3] = (short)f2bf(a0.w);
    av[4] = (short)f2bf(a1.x); av[5] = (short)f2bf(a1.y);
    av[6] = (short)f2bf(a1.z); av[7] = (short)f2bf(a1.w);
    short8_t bv = *(const short8_t*)&Wt[(size_t)(n0 + sr) * 512 + k0 + sk];
    *(short8_t*)&As[sr * 40 + sk] = av;
    *(short8_t*)&Bs[sr * 40 + sk] = bv;
    __syncthreads();
    short8_t af = *(const short8_t*)&As[(wv * 16 + lm) * 40 + qd * 8];
#pragma unroll
    for (int nt = 0; nt < 4; ++nt) {
      short8_t bf = *(const short8_t*)&Bs[(nt * 16 + lm) * 40 + qd * 8];
      acc[nt] = __builtin_amdgcn_mfma_f32_16x16x32_bf16(af, bf, acc[nt], 0, 0, 0);
    }
    __syncthreads();
  }
#pragma unroll
  for (int nt = 0; nt < 4; ++nt) {
    int col = n0 + nt * 16 + lm;
    float bb = bcat[col];
    int col2 = ((col & 255) << 2) | (col >> 8);   // gate-interleaved
#pragma unroll
    for (int r = 0; r < 4; ++r) {
      int row = m0 + wv * 16 + qd * 4 + r;
      pre[(size_t)row * 1024 + col2] = f2bf(acc[nt][r] + bb);
    }
  }
}

// ---------------------------------------------------------------------------
// Kernel 7: persistent LSTM scan — round-4 winner, VERBATIM (1092 us).
//   * Wh held in VGPRs (128/thread), loaded once from Wcat
//   * wave owns 16 h-cols x ALL 4 gates -> cell update in-register
//   * publish from registers via in-quad 4x4 shfl transpose
//   * hl double-buffered by t parity -> one barrier per step
// 16 WGs = 4 batch-groups x 4 h-blocks.  Exchange via write-once per-step
// hxT slices (bf16, 0xFF = NaN sentinel), data-polled at agent scope.
// ---------------------------------------------------------------------------
__global__ __launch_bounds__(256, 1) void scan_kernel(
    const unsigned short* __restrict__ pre,   // [32768][1024], col = h*4+g
    const unsigned short* __restrict__ Wt,    // [1024][512],  n = g*256+h
    float* __restrict__ out, unsigned long long* __restrict__ hxT)
{
  __shared__ __align__(16) unsigned short hl[2][16 * 264];  // h double-buffer
  const int tid = threadIdx.x;
  const int bg = blockIdx.x >> 2;      // batch group 0..3 (16 rows)
  const int cg = blockIdx.x & 3;       // h-block 0..3 (64 cols)
  const int lane = tid & 63;
  const int w = tid >> 6;              // wave 0..3 -> cols [w*16, w*16+16)
  const int qd = lane >> 4;
  const int lh = lane & 15;

  // zero both hl buffers (h(-1) = 0): 2*16*264 shorts = 2112 u64
  {
    unsigned long long* z = (unsigned long long*)hl;
    for (int i = tid; i < 2112; i += 256) z[i] = 0ull;
  }

  // Wh B-fragments -> VGPRs (once).  wreg[g][kc]: 16col x 32k tile fragment.
  short8_t wreg[4][8];
#pragma unroll
  for (int g = 0; g < 4; ++g)
#pragma unroll
    for (int kc = 0; kc < 8; ++kc)
      wreg[g][kc] = *(const short8_t*)&Wt[(size_t)(g * 256 + cg * 64 + w * 16 + lh) * 512
                                          + 256 + kc * 32 + qd * 8];

  const unsigned long long* pq = (const unsigned long long*)pre;
  const int orow0 = bg * 16 + qd * 4;             // this thread's 4 batch rows
  const int hcol = cg * 64 + w * 16 + lh;         // this thread's h column
  unsigned long long pcur[4], pnext[4];
#pragma unroll
  for (int r = 0; r < 4; ++r)
    pcur[r] = pq[(size_t)(orow0 + r) * 256 + hcol];

  float cst[4] = {0.f, 0.f, 0.f, 0.f};
  const int cg1 = (cg + 1) & 3, cg2 = (cg + 2) & 3, cg3 = (cg + 3) & 3;
  const int prow = tid >> 4, pcolq = tid & 15;    // poll/assemble coords

  __syncthreads();   // zeros visible

#pragma unroll 1
  for (int t = 0; t < 512; ++t) {
    unsigned long long* hlqR = (unsigned long long*)hl[t & 1];        // read buf
    unsigned long long* hlqW = (unsigned long long*)hl[(t + 1) & 1];  // write buf

    if (t > 0) {
      // poll peers' h(t-1) slices (write-once, NaN-sentinel); assemble to hlR
      const unsigned long long* sbase = hxT + (size_t)((t - 1) * 4 + bg) * 1024;
      const unsigned long long* s0 = sbase + (size_t)cg1 * 256;
      const unsigned long long* s1 = sbase + (size_t)cg2 * 256;
      const unsigned long long* s2 = sbase + (size_t)cg3 * 256;
      unsigned long long d0, d1, d2;
      bool ok;
      do {
        d0 = __hip_atomic_load(&s0[tid], __ATOMIC_RELAXED, __HIP_MEMORY_SCOPE_AGENT);
        d1 = __hip_atomic_load(&s1[tid], __ATOMIC_RELAXED, __HIP_MEMORY_SCOPE_AGENT);
        d2 = __hip_atomic_load(&s2[tid], __ATOMIC_RELAXED, __HIP_MEMORY_SCOPE_AGENT);
        ok = ((unsigned int)d0 != 0xFFFFFFFFu) && ((unsigned int)(d0 >> 32) != 0xFFFFFFFFu)
          && ((unsigned int)d1 != 0xFFFFFFFFu) && ((unsigned int)(d1 >> 32) != 0xFFFFFFFFu)
          && ((unsigned int)d2 != 0xFFFFFFFFu) && ((unsigned int)(d2 >> 32) != 0xFFFFFFFFu);
      } while (!__all((int)ok));
      hlqR[prow * 66 + cg1 * 16 + pcolq] = d0;
      hlqR[prow * 66 + cg2 * 16 + pcolq] = d1;
      hlqR[prow * 66 + cg3 * 16 + pcolq] = d2;
    }

    // prefetch pre(t+1): consumed after MFMA, one full phase of slack
    if (t < 511) {
      size_t base = (size_t)((t + 1) * 64 + orow0) * 256 + hcol;
#pragma unroll
      for (int r = 0; r < 4; ++r)
        pnext[r] = pq[base + (size_t)r * 256];
    }

    __syncthreads();   // hlR fully assembled; hlW free (all prior reads done)

    // gates(16b x 16col x 4g) = hx(16x256) @ Wh ; B from VGPRs
    const unsigned short* hb = hl[t & 1];
    floatx4 acc[4] = {{0.f,0.f,0.f,0.f},{0.f,0.f,0.f,0.f},
                      {0.f,0.f,0.f,0.f},{0.f,0.f,0.f,0.f}};
#pragma unroll
    for (int kc = 0; kc < 8; ++kc) {
      short8_t av = *(const short8_t*)&hb[lh * 264 + kc * 32 + qd * 8];
#pragma unroll
      for (int g = 0; g < 4; ++g)
        acc[g] = __builtin_amdgcn_mfma_f32_16x16x32_bf16(av, wreg[g][kc], acc[g], 0, 0, 0);
    }

    // activation + cell update (fully in-register; col = hcol, rows orow0+r)
    float h[4];
#pragma unroll
    for (int r = 0; r < 4; ++r) {
      unsigned long long pv = pcur[r];
      float xf = acc[0][r] + bf2f((unsigned short)pv);
      float xi = acc[1][r] + bf2f((unsigned short)(pv >> 16));
      float xu = acc[2][r] + bf2f((unsigned short)(pv >> 32));
      float xo = acc[3][r] + bf2f((unsigned short)(pv >> 48));
      float fg = 1.0f / (1.0f + __expf(-xf));
      float ig = 1.0f / (1.0f + __expf(-xi));
      float gg = fast_tanh(xu);
      float og = 1.0f / (1.0f + __expf(-xo));
      float cc = fg * cst[r] + ig * gg;
      cst[r] = cc;
      h[r] = og * fast_tanh(cc);
    }

    // 4x4 in-quad transpose: lane ends with row qd*4+(lane&3), 4 cols
    float t0c, t1c, t2c, t3c;
    {
      float e0 = __shfl_xor(h[0], 1);
      float e1 = __shfl_xor(h[1], 1);
      float e2 = __shfl_xor(h[2], 1);
      float e3 = __shfl_xor(h[3], 1);
      bool odd = (lane & 1);
      float b0 = odd ? e1 : h[0];
      float b1 = odd ? h[1] : e0;
      float b2 = odd ? e3 : h[2];
      float b3 = odd ? h[3] : e2;
      float f0 = __shfl_xor(b0, 2);
      float f1 = __shfl_xor(b1, 2);
      float f2 = __shfl_xor(b2, 2);
      float f3 = __shfl_xor(b3, 2);
      bool hi = (lane & 2);
      t0c = hi ? f2 : b0;
      t1c = hi ? f3 : b1;
      t2c = hi ? b2 : f0;
      t3c = hi ? b3 : f1;
    }
    unsigned long long hp = (unsigned long long)f2bf(t0c)
        | ((unsigned long long)f2bf(t1c) << 16)
        | ((unsigned long long)f2bf(t2c) << 32)
        | ((unsigned long long)f2bf(t3c) << 48);
    const int orow = qd * 4 + (lane & 3);          // transposed row 0..15
    const int ocolq = w * 4 + (lh >> 2);           // col-quad within 64-stripe

    // publish FIRST (critical path for peers), then local hlW + out
    __hip_atomic_store(&hxT[(size_t)((t * 4 + bg) * 4 + cg) * 256 + orow * 16 + ocolq],
                       hp, __ATOMIC_RELAXED, __HIP_MEMORY_SCOPE_AGENT);
    hlqW[orow * 66 + cg * 16 + ocolq] = hp;
    *(float4*)&out[(size_t)t * 16384 + (size_t)(bg * 16 + orow) * 256 + cg * 64 + ocolq * 4]
        = make_float4(t0c, t1c, t2c, t3c);

    if (t == 511) {
      const size_t hoff = (size_t)512 * 16384;
#pragma unroll
      for (int r = 0; r < 4; ++r) {
        out[hoff + (size_t)(orow0 + r) * 256 + hcol] = h[r];            // hx
        out[hoff + 16384 + (size_t)(orow0 + r) * 256 + hcol] = cst[r];  // cx
      }
    }
#pragma unroll
    for (int r = 0; r < 4; ++r) pcur[r] = pnext[r];
  }
}

// ---------------------------------------------------------------------------
extern "C" void kernel_launch(void* const* d_in, const int* in_sizes, int n_in,
                              void* d_out, int out_size, void* d_ws, size_t ws_size,
                              hipStream_t stream)
{
  const float* inputs = (const float*)d_in[0];
  const float* rot = (const float*)d_in[1];
  const float* ent = (const float*)d_in[2];
  const float* Wf = (const float*)d_in[3];
  const float* bf_ = (const float*)d_in[4];
  const float* Wi = (const float*)d_in[5];
  const float* bi_ = (const float*)d_in[6];
  const float* Wu = (const float*)d_in[7];
  const float* bu_ = (const float*)d_in[8];
  const float* Wo = (const float*)d_in[9];
  const float* bo_ = (const float*)d_in[10];
  const float* Wc = (const float*)d_in[11];
  const float* bc_ = (const float*)d_in[12];
  float* out = (float*)d_out;

  char* ws = (char*)d_ws;
  float* q  = (float*)(ws);                                   // 32 MiB [T,B,E]
  float* kb = (float*)(ws + (size_t)32 * 1024 * 1024);        // 32 MiB [T,B,E]
  float* S  = (float*)(ws + (size_t)64 * 1024 * 1024);        // 64 MiB [B,T,T]
  unsigned short* pre = (unsigned short*)S;                   // aliases S (dead)
  float* ctx = q;                                             // aliases q (dead)
  float* cp  = kb;                                            // aliases k (dead)
  // q region is dead after cp_kernel -> reuse for packed weights + hx timeline
  unsigned short* Wcat = (unsigned short*)ws;                 // 1 MiB [1024][512]
  float* bcat = (float*)(ws + (size_t)1048576);               // 4 KiB
  unsigned long long* hxT =
      (unsigned long long*)(ws + (size_t)2 * 1024 * 1024);    // 16 MiB [512][4][4][256]

  qk_kernel<<<dim3(4, 256), 256, 0, stream>>>(inputs, rot, ent, q, kb);
  scores_kernel<<<dim3(4, 4, 64), 256, 0, stream>>>(q, kb, S);
  softmax_kernel<<<dim3(32768), 256, 0, stream>>>(S);
  context_kernel<<<dim3(2, 4, 64), 256, 0, stream>>>(S, inputs, ctx);
  cp_kernel<<<dim3(4, 256), 256, 0, stream>>>(ctx, Wc, bc_, cp);
  // q region dead now: prefill hx timeline with 0xFF (bf16 NaN sentinel)
  hipMemsetAsync(hxT, 0xFF, (size_t)16 * 1024 * 1024, stream);
  pack_w<<<dim3(1024), 256, 0, stream>>>(Wf, Wi, Wu, Wo, bf_, bi_, bu_, bo_,
                                         Wcat, bcat);
  gemm_pre<<<dim3(16, 512), 256, 0, stream>>>(inputs, cp, Wcat, bcat, pre);
  scan_kernel<<<dim3(16), 256, 0, stream>>>(pre, Wcat, out, hxT);
}